// Round 2
// baseline (1644.837 us; speedup 1.0000x reference)
//
#include <hip/hip_runtime.h>
#include <hip/hip_bf16.h>

#define T 2048
#define H 2560
#define NE 8
#define ITXT 1536
#define IIMG 512
#define ISH 3072
#define CAP 2048

using bf16 = __hip_bfloat16;
typedef short short8 __attribute__((ext_vector_type(8)));
typedef float float4v __attribute__((ext_vector_type(4)));

// ---- workspace layout (bytes) ----
static constexpr size_t OFF_XBF  = 0;                                   // bf16[T*H]
static constexpr size_t OFF_CNT  = OFF_XBF + (size_t)T * H * 2;         // int[32]
static constexpr size_t OFF_TOK  = OFF_CNT + 128;                       // int[17][CAP]
static constexpr size_t OFF_WTS  = OFF_TOK + (size_t)17 * CAP * 4;      // float[17][CAP]
static constexpr size_t OFF_HTXT = OFF_WTS + (size_t)17 * CAP * 4;      // bf16[8][CAP][ITXT]
static constexpr size_t OFF_HIMG = OFF_HTXT + (size_t)NE * CAP * ITXT * 2;
static constexpr size_t OFF_HSH  = OFF_HIMG + (size_t)NE * CAP * IIMG * 2;
// bf16 transposed weights [N][K]
static constexpr size_t OFF_TGT  = OFF_HSH + (size_t)CAP * ISH * 2;     // [8][ITXT][H]
static constexpr size_t OFF_TUT  = OFF_TGT + (size_t)NE * ITXT * H * 2;
static constexpr size_t OFF_TDT  = OFF_TUT + (size_t)NE * ITXT * H * 2; // [8][H][ITXT]
static constexpr size_t OFF_IGT  = OFF_TDT + (size_t)NE * H * ITXT * 2; // [8][IIMG][H]
static constexpr size_t OFF_IUT  = OFF_IGT + (size_t)NE * IIMG * H * 2;
static constexpr size_t OFF_IDT  = OFF_IUT + (size_t)NE * IIMG * H * 2; // [8][H][IIMG]
static constexpr size_t OFF_SGT  = OFF_IDT + (size_t)NE * H * IIMG * 2; // [ISH][H]
static constexpr size_t OFF_SUT  = OFF_SGT + (size_t)ISH * H * 2;
static constexpr size_t OFF_SDT  = OFF_SUT + (size_t)ISH * H * 2;       // [H][ISH]

__device__ __forceinline__ unsigned short f2bf(float f) {
    bf16 b = __float2bfloat16(f);
    unsigned short u;
    __builtin_memcpy(&u, &b, 2);
    return u;
}

// ---- weight cast+transpose: fp32 [z][K][N] -> bf16 [z][N][K] ----
__global__ __launch_bounds__(256) void k_w2t(const float* __restrict__ in,
                                             bf16* __restrict__ out, int K, int N) {
    size_t zo = (size_t)K * N * blockIdx.z;
    in += zo; out += zo;
    __shared__ float s[64][65];
    int t = threadIdx.x;
    int k0 = blockIdx.y * 64, n0 = blockIdx.x * 64;
    int tr = t >> 4, tc = (t & 15) * 4;
#pragma unroll
    for (int p = 0; p < 4; ++p) {
        float4 v = *(const float4*)(in + (size_t)(k0 + p * 16 + tr) * N + n0 + tc);
        int r = p * 16 + tr;
        s[r][tc] = v.x; s[r][tc + 1] = v.y; s[r][tc + 2] = v.z; s[r][tc + 3] = v.w;
    }
    __syncthreads();
#pragma unroll
    for (int p = 0; p < 4; ++p) {
        int n = p * 16 + tr;
        ushort4 o;
        o.x = f2bf(s[tc + 0][n]); o.y = f2bf(s[tc + 1][n]);
        o.z = f2bf(s[tc + 2][n]); o.w = f2bf(s[tc + 3][n]);
        *(ushort4*)(out + (size_t)(n0 + n) * K + k0 + tc) = o;
    }
}

// ---- cast x to bf16 + init shared bucket ----
__global__ void k_cast_init(const float* __restrict__ x, bf16* __restrict__ xb,
                            int* __restrict__ counts, int* __restrict__ toks,
                            float* __restrict__ wts) {
    int i = blockIdx.x * blockDim.x + threadIdx.x;   // < T*H/4
    float4 v = ((const float4*)x)[i];
    ushort4 p;
    p.x = f2bf(v.x); p.y = f2bf(v.y); p.z = f2bf(v.z); p.w = f2bf(v.w);
    *(ushort4*)(xb + 4 * (size_t)i) = p;
    if (i < CAP) { toks[16 * CAP + i] = i; wts[16 * CAP + i] = 1.0f; }
    if (i == 0) counts[16] = T;
}

// ---- router: one wave per token ----
__global__ void k_router(const float* __restrict__ x, const int* __restrict__ vmask,
                         const float* __restrict__ tg, const float* __restrict__ ig,
                         int* __restrict__ counts, int* __restrict__ toks,
                         float* __restrict__ wts) {
    int wave = threadIdx.x >> 6;
    int lane = threadIdx.x & 63;
    int t = blockIdx.x * 4 + wave;
    if (t >= T) return;
    bool vis = vmask[t] != 0;
    const float* gw = vis ? ig : tg;
    const float* xr = x + (size_t)t * H;
    float logits[NE];
#pragma unroll
    for (int e = 0; e < NE; ++e) {
        const float* g = gw + (size_t)e * H;
        double s = 0.0;
        for (int h = lane; h < H; h += 64) s += (double)xr[h] * (double)g[h];
#pragma unroll
        for (int off = 32; off > 0; off >>= 1) s += __shfl_xor(s, off);
        logits[e] = (float)s;
    }
    if (lane == 0) {
        int e1 = 0;
#pragma unroll
        for (int e = 1; e < NE; ++e) if (logits[e] > logits[e1]) e1 = e;
        int e2 = -1;
#pragma unroll
        for (int e = 0; e < NE; ++e)
            if (e != e1 && (e2 < 0 || logits[e] > logits[e2])) e2 = e;
        float w1 = 1.0f / (1.0f + expf(logits[e2] - logits[e1]));
        float w2 = 1.0f - w1;
        int b = vis ? 8 : 0;
        int s1 = atomicAdd(&counts[b + e1], 1);
        toks[(b + e1) * CAP + s1] = t; wts[(b + e1) * CAP + s1] = w1;
        int s2 = atomicAdd(&counts[b + e2], 1);
        toks[(b + e2) * CAP + s2] = t; wts[(b + e2) * CAP + s2] = w2;
    }
}

// ---- grouped GEMM tiles ----
#define MT 128
#define NT 64
#define BKG 64
// LDS rows are 128B (64 bf16) = 8 x 16B slots; swizzle: slot ^= (row & 7).
// Write side: lanes (row 0..7, slot 0..7) -> bank group (slot^row)*4, each bank hit
// exactly 8x per wave-b128 -> conflict-optimal. Read side (16 lanes ride rows
// r..r+15 at fixed slot): banks (slot^(r&7))*4 distinct for 8 rows -> 2-way (free).

// Fused gate+up for all 17 buckets, bf16 [N][K] weights, 2-phase reg-staged pipeline.
__global__ __launch_bounds__(256) void k_gateup_all(
    const bf16* __restrict__ tgT, const bf16* __restrict__ tuT,
    const bf16* __restrict__ igT, const bf16* __restrict__ iuT,
    const bf16* __restrict__ sgT, const bf16* __restrict__ suT,
    const bf16* __restrict__ A,
    const int* __restrict__ counts, const int* __restrict__ toks,
    bf16* __restrict__ htxt, bf16* __restrict__ himg, bf16* __restrict__ hsh) {
    int z = blockIdx.z;
    const bf16 *bg, *bu; int N; bf16* hb;
    if (z < 8) {
        bg = tgT + (size_t)z * ITXT * H; bu = tuT + (size_t)z * ITXT * H;
        N = ITXT; hb = htxt + (size_t)z * CAP * ITXT;
    } else if (z < 16) {
        int e = z - 8;
        bg = igT + (size_t)e * IIMG * H; bu = iuT + (size_t)e * IIMG * H;
        N = IIMG; hb = himg + (size_t)e * CAP * IIMG;
    } else {
        bg = sgT; bu = suT; N = ISH; hb = hsh;
    }
    int n0 = blockIdx.x * NT;
    if (n0 >= N) return;
    int cnt = counts[z];
    int m0 = blockIdx.y * MT;
    if (m0 >= cnt) return;
    const int* tk = toks + (size_t)z * CAP + m0;

    __shared__ bf16 As[2][MT * BKG];
    __shared__ bf16 Bs[2][2][NT * BKG];

    int t = threadIdx.x, lane = t & 63, wv = t >> 6;
    int wm = wv >> 1, wn = wv & 1;

    // staging geometry (k-invariant)
    int sA = t & 7, rA = t >> 3, vA = rA & 7;
    int cl = cnt - m0 - 1;
    const bf16* aP[4]; int dA[4];
#pragma unroll
    for (int h = 0; h < 4; ++h) {
        int r = rA + h * 32;
        int rr = r < cl ? r : cl;
        aP[h] = A + (size_t)tk[rr] * H + sA * 8;
        dA[h] = r * BKG + ((sA ^ vA) << 3);
    }
    int nB = t >> 2, sB = (t & 3) * 2, vB = nB & 7;
    const bf16* gP = bg + (size_t)(n0 + nB) * H + sB * 8;
    const bf16* uP = bu + (size_t)(n0 + nB) * H + sB * 8;
    int dB0 = nB * BKG + (((sB) ^ vB) << 3);
    int dB1 = nB * BKG + (((sB + 1) ^ vB) << 3);

    // fragment read offsets
    int fr = lane & 15, hi = lane >> 4, vF = fr & 7;
    int oA[4][2], oB[2][2];
#pragma unroll
    for (int i = 0; i < 4; ++i)
#pragma unroll
        for (int s = 0; s < 2; ++s)
            oA[i][s] = (wm * 64 + i * 16 + fr) * BKG + (((s * 4 + hi) ^ vF) << 3);
#pragma unroll
    for (int j = 0; j < 2; ++j)
#pragma unroll
        for (int s = 0; s < 2; ++s)
            oB[j][s] = (wn * 32 + j * 16 + fr) * BKG + (((s * 4 + hi) ^ vF) << 3);

    float4v accg[4][2], accu[4][2];
#pragma unroll
    for (int i = 0; i < 4; ++i)
#pragma unroll
        for (int j = 0; j < 2; ++j) { accg[i][j] = (float4v)0.0f; accu[i][j] = (float4v)0.0f; }

    uint4 a_[4], g_[2], u_[2];
    auto LOADR = [&](int k0) {
#pragma unroll
        for (int h = 0; h < 4; ++h) a_[h] = *(const uint4*)(aP[h] + k0);
        g_[0] = *(const uint4*)(gP + k0); g_[1] = *(const uint4*)(gP + k0 + 8);
        u_[0] = *(const uint4*)(uP + k0); u_[1] = *(const uint4*)(uP + k0 + 8);
    };
    auto STORER = [&](int buf) {
#pragma unroll
        for (int h = 0; h < 4; ++h) *(uint4*)&As[buf][dA[h]] = a_[h];
        *(uint4*)&Bs[buf][0][dB0] = g_[0]; *(uint4*)&Bs[buf][0][dB1] = g_[1];
        *(uint4*)&Bs[buf][1][dB0] = u_[0]; *(uint4*)&Bs[buf][1][dB1] = u_[1];
    };

    LOADR(0);
    STORER(0);
    int cur = 0;
    for (int k0 = 0; k0 < H; k0 += BKG) {
        __syncthreads();
        bool more = (k0 + BKG) < H;
        if (more) LOADR(k0 + BKG);
#pragma unroll
        for (int s = 0; s < 2; ++s) {
            short8 af[4], bgf[2], buf_[2];
#pragma unroll
            for (int i = 0; i < 4; ++i) af[i] = *(const short8*)&As[cur][oA[i][s]];
#pragma unroll
            for (int j = 0; j < 2; ++j) {
                bgf[j]  = *(const short8*)&Bs[cur][0][oB[j][s]];
                buf_[j] = *(const short8*)&Bs[cur][1][oB[j][s]];
            }
#pragma unroll
            for (int i = 0; i < 4; ++i)
#pragma unroll
                for (int j = 0; j < 2; ++j) {
                    accg[i][j] = __builtin_amdgcn_mfma_f32_16x16x32_bf16(af[i], bgf[j],  accg[i][j], 0, 0, 0);
                    accu[i][j] = __builtin_amdgcn_mfma_f32_16x16x32_bf16(af[i], buf_[j], accu[i][j], 0, 0, 0);
                }
        }
        if (more) STORER(cur ^ 1);
        cur ^= 1;
    }

    int rbase = hi << 2;
    int cc = fr;
#pragma unroll
    for (int i = 0; i < 4; ++i)
#pragma unroll
        for (int j = 0; j < 2; ++j)
#pragma unroll
            for (int r = 0; r < 4; ++r) {
                int ml = m0 + wm * 64 + i * 16 + rbase + r;
                if (ml < cnt) {
                    int col = n0 + wn * 32 + j * 16 + cc;
                    float g = accg[i][j][r], u = accu[i][j][r];
                    float hv = g / (1.0f + expf(-g)) * u;
                    hb[(size_t)ml * N + col] = __float2bfloat16(hv);
                }
            }
}

// Down-proj. SH=true: shared expert only, plain stores (covers every out element).
// SH=false: routed buckets z=0..15, atomicAdd on top.
template <bool SH>
__global__ __launch_bounds__(256) void k_down(
    const bf16* __restrict__ tdT, const bf16* __restrict__ idT, const bf16* __restrict__ sdT,
    const bf16* __restrict__ htxt, const bf16* __restrict__ himg, const bf16* __restrict__ hsh,
    const int* __restrict__ counts, const int* __restrict__ toks,
    const float* __restrict__ wts,
    float* __restrict__ out) {
    int z = SH ? 16 : blockIdx.z;
    const bf16 *bw, *Ab; int K, cnt;
    if (SH) { bw = sdT; Ab = hsh; K = ISH; cnt = T; }
    else if (z < 8) { bw = tdT + (size_t)z * H * ITXT; Ab = htxt + (size_t)z * CAP * ITXT; K = ITXT; cnt = counts[z]; }
    else { int e = z - 8; bw = idT + (size_t)e * H * IIMG; Ab = himg + (size_t)e * CAP * IIMG; K = IIMG; cnt = counts[z]; }
    int m0 = blockIdx.y * MT;
    if (m0 >= cnt) return;
    int n0 = blockIdx.x * NT;   // N = H

    __shared__ bf16 As[2][MT * BKG];
    __shared__ bf16 Bs[2][NT * BKG];

    int t = threadIdx.x, lane = t & 63, wv = t >> 6;
    int wm = wv >> 1, wn = wv & 1;

    int sA = t & 7, rA = t >> 3, vA = rA & 7;
    const bf16* aP[4]; int dA[4];
#pragma unroll
    for (int h = 0; h < 4; ++h) {
        int r = rA + h * 32;
        aP[h] = Ab + (size_t)(m0 + r) * K + sA * 8;   // rows >= cnt read garbage, never stored
        dA[h] = r * BKG + ((sA ^ vA) << 3);
    }
    int nB = t >> 2, sB = (t & 3) * 2, vB = nB & 7;
    const bf16* bP = bw + (size_t)(n0 + nB) * K + sB * 8;
    int dB0 = nB * BKG + (((sB) ^ vB) << 3);
    int dB1 = nB * BKG + (((sB + 1) ^ vB) << 3);

    int fr = lane & 15, hi = lane >> 4, vF = fr & 7;
    int oA[4][2], oB[2][2];
#pragma unroll
    for (int i = 0; i < 4; ++i)
#pragma unroll
        for (int s = 0; s < 2; ++s)
            oA[i][s] = (wm * 64 + i * 16 + fr) * BKG + (((s * 4 + hi) ^ vF) << 3);
#pragma unroll
    for (int j = 0; j < 2; ++j)
#pragma unroll
        for (int s = 0; s < 2; ++s)
            oB[j][s] = (wn * 32 + j * 16 + fr) * BKG + (((s * 4 + hi) ^ vF) << 3);

    float4v acc[4][2];
#pragma unroll
    for (int i = 0; i < 4; ++i)
#pragma unroll
        for (int j = 0; j < 2; ++j) acc[i][j] = (float4v)0.0f;

    uint4 a_[4], b_[2];
    auto LOADR = [&](int k0) {
#pragma unroll
        for (int h = 0; h < 4; ++h) a_[h] = *(const uint4*)(aP[h] + k0);
        b_[0] = *(const uint4*)(bP + k0); b_[1] = *(const uint4*)(bP + k0 + 8);
    };
    auto STORER = [&](int buf) {
#pragma unroll
        for (int h = 0; h < 4; ++h) *(uint4*)&As[buf][dA[h]] = a_[h];
        *(uint4*)&Bs[buf][dB0] = b_[0]; *(uint4*)&Bs[buf][dB1] = b_[1];
    };

    LOADR(0);
    STORER(0);
    int cur = 0;
    for (int k0 = 0; k0 < K; k0 += BKG) {
        __syncthreads();
        bool more = (k0 + BKG) < K;
        if (more) LOADR(k0 + BKG);
#pragma unroll
        for (int s = 0; s < 2; ++s) {
            short8 af[4], bf_[2];
#pragma unroll
            for (int i = 0; i < 4; ++i) af[i] = *(const short8*)&As[cur][oA[i][s]];
#pragma unroll
            for (int j = 0; j < 2; ++j) bf_[j] = *(const short8*)&Bs[cur][oB[j][s]];
#pragma unroll
            for (int i = 0; i < 4; ++i)
#pragma unroll
                for (int j = 0; j < 2; ++j)
                    acc[i][j] = __builtin_amdgcn_mfma_f32_16x16x32_bf16(af[i], bf_[j], acc[i][j], 0, 0, 0);
        }
        if (more) STORER(cur ^ 1);
        cur ^= 1;
    }

    int rbase = hi << 2;
    int cc = fr;
    const int* tkl = toks + (size_t)z * CAP;
    const float* wl = wts + (size_t)z * CAP;
#pragma unroll
    for (int i = 0; i < 4; ++i)
#pragma unroll
        for (int j = 0; j < 2; ++j)
#pragma unroll
            for (int r = 0; r < 4; ++r) {
                int ml = m0 + wm * 64 + i * 16 + rbase + r;
                if (ml < cnt) {
                    int col = n0 + wn * 32 + j * 16 + cc;
                    if (SH) {
                        out[(size_t)ml * H + col] = acc[i][j][r];
                    } else {
                        atomicAdd(&out[(size_t)tkl[ml] * H + col], acc[i][j][r] * wl[ml]);
                    }
                }
            }
}

extern "C" void kernel_launch(void* const* d_in, const int* in_sizes, int n_in,
                              void* d_out, int out_size, void* d_ws, size_t ws_size,
                              hipStream_t stream) {
    const float* x    = (const float*)d_in[0];
    const int*   vm   = (const int*)d_in[1];
    const float* tg   = (const float*)d_in[2];
    const float* twg  = (const float*)d_in[3];
    const float* twu  = (const float*)d_in[4];
    const float* twd  = (const float*)d_in[5];
    const float* ig   = (const float*)d_in[6];
    const float* iwg  = (const float*)d_in[7];
    const float* iwu  = (const float*)d_in[8];
    const float* iwd  = (const float*)d_in[9];
    const float* swg  = (const float*)d_in[10];
    const float* swu  = (const float*)d_in[11];
    const float* swd  = (const float*)d_in[12];
    float* out = (float*)d_out;
    char* ws = (char*)d_ws;

    bf16* xb     = (bf16*)(ws + OFF_XBF);
    int*  counts = (int*)(ws + OFF_CNT);
    int*  toks   = (int*)(ws + OFF_TOK);
    float* wtsp  = (float*)(ws + OFF_WTS);
    bf16* htxt   = (bf16*)(ws + OFF_HTXT);
    bf16* himg   = (bf16*)(ws + OFF_HIMG);
    bf16* hsh    = (bf16*)(ws + OFF_HSH);
    bf16* tgT    = (bf16*)(ws + OFF_TGT);
    bf16* tuT    = (bf16*)(ws + OFF_TUT);
    bf16* tdT    = (bf16*)(ws + OFF_TDT);
    bf16* igT    = (bf16*)(ws + OFF_IGT);
    bf16* iuT    = (bf16*)(ws + OFF_IUT);
    bf16* idT    = (bf16*)(ws + OFF_IDT);
    bf16* sgT    = (bf16*)(ws + OFF_SGT);
    bf16* suT    = (bf16*)(ws + OFF_SUT);
    bf16* sdT    = (bf16*)(ws + OFF_SDT);

    hipMemsetAsync(counts, 0, 128, stream);

    // weight cast+transpose (independent of x)
    k_w2t<<<dim3(ITXT / 64, H / 64, NE), dim3(256), 0, stream>>>(twg, tgT, H, ITXT);
    k_w2t<<<dim3(ITXT / 64, H / 64, NE), dim3(256), 0, stream>>>(twu, tuT, H, ITXT);
    k_w2t<<<dim3(H / 64, ITXT / 64, NE), dim3(256), 0, stream>>>(twd, tdT, ITXT, H);
    k_w2t<<<dim3(IIMG / 64, H / 64, NE), dim3(256), 0, stream>>>(iwg, igT, H, IIMG);
    k_w2t<<<dim3(IIMG / 64, H / 64, NE), dim3(256), 0, stream>>>(iwu, iuT, H, IIMG);
    k_w2t<<<dim3(H / 64, IIMG / 64, NE), dim3(256), 0, stream>>>(iwd, idT, IIMG, H);
    k_w2t<<<dim3(ISH / 64, H / 64, 1), dim3(256), 0, stream>>>(swg, sgT, H, ISH);
    k_w2t<<<dim3(ISH / 64, H / 64, 1), dim3(256), 0, stream>>>(swu, suT, H, ISH);
    k_w2t<<<dim3(H / 64, ISH / 64, 1), dim3(256), 0, stream>>>(swd, sdT, ISH, H);

    k_cast_init<<<dim3((T * H / 4) / 256), dim3(256), 0, stream>>>(x, xb, counts, toks, wtsp);
    k_router<<<dim3(T / 4), dim3(256), 0, stream>>>(x, vm, tg, ig, counts, toks, wtsp);

    k_gateup_all<<<dim3(ISH / NT, CAP / MT, 17), dim3(256), 0, stream>>>(
        tgT, tuT, igT, iuT, sgT, suT, xb, counts, toks, htxt, himg, hsh);

    // shared first: plain stores cover every out element (no memset of out needed)
    k_down<true><<<dim3(H / NT, CAP / MT, 1), dim3(256), 0, stream>>>(
        tdT, idT, sdT, htxt, himg, hsh, counts, toks, wtsp, out);
    // routed on top: atomicAdd
    k_down<false><<<dim3(H / NT, CAP / MT, 16), dim3(256), 0, stream>>>(
        tdT, idT, sdT, htxt, himg, hsh, counts, toks, wtsp, out);
}

// Round 3
// 1073.740 us; speedup vs baseline: 1.5319x; 1.5319x over previous
//
#include <hip/hip_runtime.h>
#include <hip/hip_bf16.h>

#define T 2048
#define H 2560
#define NE 8
#define ITXT 1536
#define IIMG 512
#define ISH 3072
#define CAP 2048

using bf16 = __hip_bfloat16;
typedef short short8 __attribute__((ext_vector_type(8)));
typedef float float4v __attribute__((ext_vector_type(4)));

// ---- workspace layout (bytes) ----
static constexpr size_t OFF_XBF  = 0;                                   // bf16[T*H]
static constexpr size_t OFF_CNT  = OFF_XBF + (size_t)T * H * 2;         // int[32]
static constexpr size_t OFF_TOK  = OFF_CNT + 128;                       // int[17][CAP]
static constexpr size_t OFF_WTS  = OFF_TOK + (size_t)17 * CAP * 4;      // float[17][CAP]
static constexpr size_t OFF_HTXT = OFF_WTS + (size_t)17 * CAP * 4;      // bf16[8][CAP][ITXT]
static constexpr size_t OFF_HIMG = OFF_HTXT + (size_t)NE * CAP * ITXT * 2;
static constexpr size_t OFF_HSH  = OFF_HIMG + (size_t)NE * CAP * IIMG * 2;

__device__ __forceinline__ unsigned short f2bf(float f) {
    bf16 b = __float2bfloat16(f);
    unsigned short u;
    __builtin_memcpy(&u, &b, 2);
    return u;
}
__device__ __forceinline__ unsigned pk2(float a, float b) {
    return (unsigned)f2bf(a) | ((unsigned)f2bf(b) << 16);
}

// ---- cast x to bf16 + init shared bucket ----
__global__ void k_cast_init(const float* __restrict__ x, bf16* __restrict__ xb,
                            int* __restrict__ counts, int* __restrict__ toks,
                            float* __restrict__ wts) {
    int i = blockIdx.x * blockDim.x + threadIdx.x;   // < T*H/4
    float4 v = ((const float4*)x)[i];
    ushort4 p;
    p.x = f2bf(v.x); p.y = f2bf(v.y); p.z = f2bf(v.z); p.w = f2bf(v.w);
    *(ushort4*)(xb + 4 * (size_t)i) = p;
    if (i < CAP) { toks[16 * CAP + i] = i; wts[16 * CAP + i] = 1.0f; }
    if (i == 0) counts[16] = T;
}

// ---- router: one wave per token ----
__global__ void k_router(const float* __restrict__ x, const int* __restrict__ vmask,
                         const float* __restrict__ tg, const float* __restrict__ ig,
                         int* __restrict__ counts, int* __restrict__ toks,
                         float* __restrict__ wts) {
    int wave = threadIdx.x >> 6;
    int lane = threadIdx.x & 63;
    int t = blockIdx.x * 4 + wave;
    if (t >= T) return;
    bool vis = vmask[t] != 0;
    const float* gw = vis ? ig : tg;
    const float* xr = x + (size_t)t * H;
    float logits[NE];
#pragma unroll
    for (int e = 0; e < NE; ++e) {
        const float* g = gw + (size_t)e * H;
        double s = 0.0;
        for (int h = lane; h < H; h += 64) s += (double)xr[h] * (double)g[h];
#pragma unroll
        for (int off = 32; off > 0; off >>= 1) s += __shfl_xor(s, off);
        logits[e] = (float)s;
    }
    if (lane == 0) {
        int e1 = 0;
#pragma unroll
        for (int e = 1; e < NE; ++e) if (logits[e] > logits[e1]) e1 = e;
        int e2 = -1;
#pragma unroll
        for (int e = 0; e < NE; ++e)
            if (e != e1 && (e2 < 0 || logits[e] > logits[e2])) e2 = e;
        float w1 = 1.0f / (1.0f + expf(logits[e2] - logits[e1]));
        float w2 = 1.0f - w1;
        int b = vis ? 8 : 0;
        int s1 = atomicAdd(&counts[b + e1], 1);
        toks[(b + e1) * CAP + s1] = t; wts[(b + e1) * CAP + s1] = w1;
        int s2 = atomicAdd(&counts[b + e2], 1);
        toks[(b + e2) * CAP + s2] = t; wts[(b + e2) * CAP + s2] = w2;
    }
}

// ---- grouped GEMM tiles ----
#define MT 128
#define NT 64
#define BK 32
// LDS rows = 32 bf16 = 64B = 4 x 16B slots; swizzle slot ^= (row>>1)&3.
// Write/read both land on 8 distinct start-banks x 8 beats -> conflict-free.

// Fused gate+up for all 17 buckets; fp32 weights converted in-register during staging.
// 3-stage pipeline: regs hold tile k+1 while MFMA runs on LDS tile k; loads for k+2
// issue after the k+1 LDS write -> vmcnt slack = one full iteration.
__global__ __launch_bounds__(256) void k_gateup_all(
    const float* __restrict__ twg, const float* __restrict__ twu,
    const float* __restrict__ iwg, const float* __restrict__ iwu,
    const float* __restrict__ swg, const float* __restrict__ swu,
    const bf16* __restrict__ A,
    const int* __restrict__ counts, const int* __restrict__ toks,
    bf16* __restrict__ htxt, bf16* __restrict__ himg, bf16* __restrict__ hsh) {
    int z = blockIdx.z;
    const float *bg, *bu; int N; bf16* hb;
    if (z < 8) {
        bg = twg + (size_t)z * H * ITXT; bu = twu + (size_t)z * H * ITXT;
        N = ITXT; hb = htxt + (size_t)z * CAP * ITXT;
    } else if (z < 16) {
        int e = z - 8;
        bg = iwg + (size_t)e * H * IIMG; bu = iwu + (size_t)e * H * IIMG;
        N = IIMG; hb = himg + (size_t)e * CAP * IIMG;
    } else {
        bg = swg; bu = swu; N = ISH; hb = hsh;
    }
    int n0 = blockIdx.x * NT;
    if (n0 >= N) return;
    int cnt = counts[z];
    int m0 = blockIdx.y * MT;
    if (m0 >= cnt) return;
    const int* tk = toks + (size_t)z * CAP + m0;

    __shared__ bf16 As[2][MT * BK];
    __shared__ bf16 Bs[2][2][NT * BK];

    int t = threadIdx.x, lane = t & 63, wv = t >> 6;
    int wm = wv >> 1, wn = wv & 1;

    // --- A staging geometry: thread -> (row rA, 16-elem half hA) ---
    int rA = t >> 1, hA = t & 1;
    int cl = cnt - m0 - 1;
    int rr = rA < cl ? rA : cl;
    const bf16* aP = A + (size_t)tk[rr] * H + hA * 16;
    int swA = (rA >> 1) & 3;
    int dA0 = rA * BK + ((2 * hA) ^ swA) * 8;
    int dA1 = rA * BK + ((2 * hA + 1) ^ swA) * 8;

    // --- B staging geometry: thread -> one n-row, 16 k-elems of g or u ---
    int nB = t & 63, sel = t >> 6;
    int mat = sel >> 1, kh = sel & 1;          // mat 0=gate,1=up ; kh = k-half (16)
    const float* bBase = (mat ? bu : bg) + (size_t)(kh * 16) * N + n0 + nB;
    int swB = (nB >> 1) & 3;
    int dB0 = nB * BK + ((2 * kh) ^ swB) * 8;
    int dB1 = nB * BK + ((2 * kh + 1) ^ swB) * 8;

    // --- fragment read offsets ---
    int fr = lane & 15, hi = lane >> 4;
    int swF = (fr >> 1) & 3;
    int fo = (hi ^ swF) * 8;
    int oA[4], oB[2];
#pragma unroll
    for (int i = 0; i < 4; ++i) oA[i] = (wm * 64 + i * 16 + fr) * BK + fo;
#pragma unroll
    for (int j = 0; j < 2; ++j) oB[j] = (wn * 32 + j * 16 + fr) * BK + fo;

    float4v accg[4][2], accu[4][2];
#pragma unroll
    for (int i = 0; i < 4; ++i)
#pragma unroll
        for (int j = 0; j < 2; ++j) { accg[i][j] = (float4v)0.0f; accu[i][j] = (float4v)0.0f; }

    uint4 a0, a1;
    float bv[16];
    auto LOADR = [&](int k0) {
        a0 = *(const uint4*)(aP + k0);
        a1 = *(const uint4*)(aP + k0 + 8);
        const float* p = bBase + (size_t)k0 * N;
#pragma unroll
        for (int i = 0; i < 16; ++i) { bv[i] = *p; p += N; }
    };
    auto STORER = [&](int buf) {
        *(uint4*)&As[buf][dA0] = a0;
        *(uint4*)&As[buf][dA1] = a1;
        uint4 q0, q1;
        q0.x = pk2(bv[0], bv[1]);  q0.y = pk2(bv[2], bv[3]);
        q0.z = pk2(bv[4], bv[5]);  q0.w = pk2(bv[6], bv[7]);
        q1.x = pk2(bv[8], bv[9]);  q1.y = pk2(bv[10], bv[11]);
        q1.z = pk2(bv[12], bv[13]); q1.w = pk2(bv[14], bv[15]);
        *(uint4*)&Bs[buf][mat][dB0] = q0;
        *(uint4*)&Bs[buf][mat][dB1] = q1;
    };

    LOADR(0);
    STORER(0);
    LOADR(BK);
    int cur = 0;
    for (int k0 = 0; k0 < H; k0 += BK) {
        __syncthreads();
        short8 af[4], bgf[2], buf_[2];
#pragma unroll
        for (int i = 0; i < 4; ++i) af[i] = *(const short8*)&As[cur][oA[i]];
#pragma unroll
        for (int j = 0; j < 2; ++j) {
            bgf[j]  = *(const short8*)&Bs[cur][0][oB[j]];
            buf_[j] = *(const short8*)&Bs[cur][1][oB[j]];
        }
#pragma unroll
        for (int i = 0; i < 4; ++i)
#pragma unroll
            for (int j = 0; j < 2; ++j) {
                accg[i][j] = __builtin_amdgcn_mfma_f32_16x16x32_bf16(af[i], bgf[j],  accg[i][j], 0, 0, 0);
                accu[i][j] = __builtin_amdgcn_mfma_f32_16x16x32_bf16(af[i], buf_[j], accu[i][j], 0, 0, 0);
            }
        if (k0 + BK < H) {
            STORER(cur ^ 1);                 // regs from previous LOADR (full-iter slack)
            if (k0 + 2 * BK < H) LOADR(k0 + 2 * BK);
            cur ^= 1;
        }
    }

    int rbase = hi << 2;
    int cc = fr;
#pragma unroll
    for (int i = 0; i < 4; ++i)
#pragma unroll
        for (int j = 0; j < 2; ++j)
#pragma unroll
            for (int r = 0; r < 4; ++r) {
                int ml = m0 + wm * 64 + i * 16 + rbase + r;
                if (ml < cnt) {
                    int col = n0 + wn * 32 + j * 16 + cc;
                    float g = accg[i][j][r], u = accu[i][j][r];
                    float hv = g / (1.0f + expf(-g)) * u;
                    hb[(size_t)ml * N + col] = __float2bfloat16(hv);
                }
            }
}

// Fused down-proj for all 17 buckets; same pipeline; atomicAdd into pre-zeroed out.
__global__ __launch_bounds__(256) void k_down_all(
    const float* __restrict__ twd, const float* __restrict__ iwd, const float* __restrict__ swd,
    const bf16* __restrict__ htxt, const bf16* __restrict__ himg, const bf16* __restrict__ hsh,
    const int* __restrict__ counts, const int* __restrict__ toks,
    const float* __restrict__ wts,
    float* __restrict__ out) {
    int z = blockIdx.z;
    const float* bw; const bf16* Ab; int K, cnt;
    if (z < 8) { bw = twd + (size_t)z * ITXT * H; Ab = htxt + (size_t)z * CAP * ITXT; K = ITXT; cnt = counts[z]; }
    else if (z < 16) { int e = z - 8; bw = iwd + (size_t)e * IIMG * H; Ab = himg + (size_t)e * CAP * IIMG; K = IIMG; cnt = counts[z]; }
    else { bw = swd; Ab = hsh; K = ISH; cnt = T; }
    int m0 = blockIdx.y * MT;
    if (m0 >= cnt) return;
    int n0 = blockIdx.x * NT;   // N = H always

    __shared__ bf16 As[2][MT * BK];
    __shared__ bf16 Bs[2][NT * BK];

    int t = threadIdx.x, lane = t & 63, wv = t >> 6;
    int wm = wv >> 1, wn = wv & 1;

    int rA = t >> 1, hA = t & 1;
    const bf16* aP = Ab + (size_t)(m0 + rA) * K + hA * 16;  // rows>=cnt read garbage, never stored
    int swA = (rA >> 1) & 3;
    int dA0 = rA * BK + ((2 * hA) ^ swA) * 8;
    int dA1 = rA * BK + ((2 * hA + 1) ^ swA) * 8;

    int nB = t & 63, kq = t >> 6;             // kq = k-quarter (8 elems)
    const float* bBase = bw + (size_t)(kq * 8) * H + n0 + nB;
    int swB = (nB >> 1) & 3;
    int dB0 = nB * BK + (kq ^ swB) * 8;

    int fr = lane & 15, hi = lane >> 4;
    int swF = (fr >> 1) & 3;
    int fo = (hi ^ swF) * 8;
    int oA[4], oB[2];
#pragma unroll
    for (int i = 0; i < 4; ++i) oA[i] = (wm * 64 + i * 16 + fr) * BK + fo;
#pragma unroll
    for (int j = 0; j < 2; ++j) oB[j] = (wn * 32 + j * 16 + fr) * BK + fo;

    float4v acc[4][2];
#pragma unroll
    for (int i = 0; i < 4; ++i)
#pragma unroll
        for (int j = 0; j < 2; ++j) acc[i][j] = (float4v)0.0f;

    uint4 a0, a1;
    float bv[8];
    auto LOADR = [&](int k0) {
        a0 = *(const uint4*)(aP + k0);
        a1 = *(const uint4*)(aP + k0 + 8);
        const float* p = bBase + (size_t)k0 * H;
#pragma unroll
        for (int i = 0; i < 8; ++i) { bv[i] = *p; p += H; }
    };
    auto STORER = [&](int buf) {
        *(uint4*)&As[buf][dA0] = a0;
        *(uint4*)&As[buf][dA1] = a1;
        uint4 q0;
        q0.x = pk2(bv[0], bv[1]); q0.y = pk2(bv[2], bv[3]);
        q0.z = pk2(bv[4], bv[5]); q0.w = pk2(bv[6], bv[7]);
        *(uint4*)&Bs[buf][dB0] = q0;
    };

    LOADR(0);
    STORER(0);
    LOADR(BK);
    int cur = 0;
    for (int k0 = 0; k0 < K; k0 += BK) {
        __syncthreads();
        short8 af[4], bf_[2];
#pragma unroll
        for (int i = 0; i < 4; ++i) af[i] = *(const short8*)&As[cur][oA[i]];
#pragma unroll
        for (int j = 0; j < 2; ++j) bf_[j] = *(const short8*)&Bs[cur][oB[j]];
#pragma unroll
        for (int i = 0; i < 4; ++i)
#pragma unroll
            for (int j = 0; j < 2; ++j)
                acc[i][j] = __builtin_amdgcn_mfma_f32_16x16x32_bf16(af[i], bf_[j], acc[i][j], 0, 0, 0);
        if (k0 + BK < K) {
            STORER(cur ^ 1);
            if (k0 + 2 * BK < K) LOADR(k0 + 2 * BK);
            cur ^= 1;
        }
    }

    int rbase = hi << 2;
    int cc = fr;
    const int* tkl = toks + (size_t)z * CAP;
    const float* wl = wts + (size_t)z * CAP;
#pragma unroll
    for (int i = 0; i < 4; ++i)
#pragma unroll
        for (int j = 0; j < 2; ++j)
#pragma unroll
            for (int r = 0; r < 4; ++r) {
                int ml = m0 + wm * 64 + i * 16 + rbase + r;
                if (ml < cnt) {
                    int col = n0 + wn * 32 + j * 16 + cc;
                    int tok = tkl[ml];
                    atomicAdd(&out[(size_t)tok * H + col], acc[i][j][r] * wl[ml]);
                }
            }
}

extern "C" void kernel_launch(void* const* d_in, const int* in_sizes, int n_in,
                              void* d_out, int out_size, void* d_ws, size_t ws_size,
                              hipStream_t stream) {
    const float* x    = (const float*)d_in[0];
    const int*   vm   = (const int*)d_in[1];
    const float* tg   = (const float*)d_in[2];
    const float* twg  = (const float*)d_in[3];
    const float* twu  = (const float*)d_in[4];
    const float* twd  = (const float*)d_in[5];
    const float* ig   = (const float*)d_in[6];
    const float* iwg  = (const float*)d_in[7];
    const float* iwu  = (const float*)d_in[8];
    const float* iwd  = (const float*)d_in[9];
    const float* swg  = (const float*)d_in[10];
    const float* swu  = (const float*)d_in[11];
    const float* swd  = (const float*)d_in[12];
    float* out = (float*)d_out;
    char* ws = (char*)d_ws;

    bf16* xb     = (bf16*)(ws + OFF_XBF);
    int*  counts = (int*)(ws + OFF_CNT);
    int*  toks   = (int*)(ws + OFF_TOK);
    float* wtsp  = (float*)(ws + OFF_WTS);
    bf16* htxt   = (bf16*)(ws + OFF_HTXT);
    bf16* himg   = (bf16*)(ws + OFF_HIMG);
    bf16* hsh    = (bf16*)(ws + OFF_HSH);

    hipMemsetAsync(counts, 0, 128, stream);
    hipMemsetAsync(out, 0, (size_t)T * H * sizeof(float), stream);

    k_cast_init<<<dim3((T * H / 4) / 256), dim3(256), 0, stream>>>(x, xb, counts, toks, wtsp);
    k_router<<<dim3(T / 4), dim3(256), 0, stream>>>(x, vm, tg, ig, counts, toks, wtsp);

    k_gateup_all<<<dim3(ISH / NT, CAP / MT, 17), dim3(256), 0, stream>>>(
        twg, twu, iwg, iwu, swg, swu, xb, counts, toks, htxt, himg, hsh);

    k_down_all<<<dim3(H / NT, CAP / MT, 17), dim3(256), 0, stream>>>(
        twd, iwd, swd, htxt, himg, hsh, counts, toks, wtsp, out);
}